// Round 3
// baseline (850.236 us; speedup 1.0000x reference)
//
#include <hip/hip_runtime.h>

typedef _Float16 f16;
typedef _Float16 f16x4 __attribute__((ext_vector_type(4)));
typedef _Float16 f16x8 __attribute__((ext_vector_type(8)));
typedef float    f32x4 __attribute__((ext_vector_type(4)));

static constexpr int H  = 128;
static constexpr int MT = 128;          // edges per block
static constexpr int PA = 136;          // act row stride in halves (16B-aligned: 272 B)
static constexpr int W0T_OFF = 0;                       // halves into ws
static constexpr int W1T_OFF = 128 * 384;
static constexpr int W2T_OFF = 128 * 384 + 128 * 128;   // total 81920 halves = 160 KB

// ---- prep: W (K x 128 f32, row-major) -> W^T (128 x K f16, k-contig) in ws ----
__global__ __launch_bounds__(256)
void prep_weights(const float* __restrict__ W0,
                  const float* __restrict__ W1,
                  const float* __restrict__ W2,
                  f16* __restrict__ o)
{
    int tid = blockIdx.x * 256 + threadIdx.x;
    const float* W; f16* dst; int K, idx;
    if (tid < 12288)      { W = W0; dst = o + W0T_OFF; K = 384; idx = tid; }
    else if (tid < 16384) { W = W1; dst = o + W1T_OFF; K = 128; idx = tid - 12288; }
    else if (tid < 20480) { W = W2; dst = o + W2T_OFF; K = 128; idx = tid - 16384; }
    else return;
    int n  = idx & 127;       // coalesced along n
    int k4 = idx >> 7;
    f16x4 v;
    #pragma unroll
    for (int j = 0; j < 4; ++j) v[j] = (f16)W[(k4 * 4 + j) * H + n];
    *(f16x4*)&dst[n * K + k4 * 4] = v;
}

// ---- fused edge MLP: zero barriers, wave-private M=32 tiles ----
__global__ __launch_bounds__(256, 4)
void edge_mlp(const float* __restrict__ x,
              const int* __restrict__ eidx,
              const float* __restrict__ edge,
              const f16* __restrict__ wsW,
              const float* __restrict__ b0, const float* __restrict__ g0, const float* __restrict__ be0,
              const float* __restrict__ b1, const float* __restrict__ g1, const float* __restrict__ be1,
              const float* __restrict__ b2, const float* __restrict__ g2, const float* __restrict__ be2,
              const float* __restrict__ W3, const float* __restrict__ b3,
              float* __restrict__ out, int E)
{
    __shared__ f16 act[MT * PA];   // 34816 B -> 4 blocks/CU

    const int tid  = threadIdx.x;
    const int lane = tid & 63;
    const int wid  = tid >> 6;
    const int c    = lane & 15;    // MFMA 16-dim coord
    const int g    = lane >> 4;    // quad group 0..3
    const int wrow = wid * 32;
    const long long e0 = (long long)blockIdx.x * MT;

    // this lane's two A-fragment rows (edges wrow+c and wrow+16+c)
    long long ea = e0 + wrow + c;      if (ea >= E) ea = (long long)E - 1;
    long long eb = e0 + wrow + 16 + c; if (eb >= E) eb = (long long)E - 1;
    const float* sp0 = x + (size_t)eidx[ea] * H;
    const float* sp1 = x + (size_t)eidx[eb] * H;
    const float* dp0 = x + (size_t)eidx[E + ea] * H;
    const float* dp1 = x + (size_t)eidx[E + eb] * H;
    const float* ep0 = edge + (size_t)ea * H;
    const float* ep1 = edge + (size_t)eb * H;

    f32x4 acc[8][2];
    #pragma unroll
    for (int t = 0; t < 8; ++t) {
        acc[t][0] = f32x4{0.f, 0.f, 0.f, 0.f};
        acc[t][1] = f32x4{0.f, 0.f, 0.f, 0.f};
    }

    auto load_a = [&](const float* p, int off) -> f16x8 {
        float4 u = *(const float4*)(p + off);
        float4 v = *(const float4*)(p + off + 4);
        f16x8 a;
        a[0] = (f16)u.x; a[1] = (f16)u.y; a[2] = (f16)u.z; a[3] = (f16)u.w;
        a[4] = (f16)v.x; a[5] = (f16)v.y; a[6] = (f16)v.z; a[7] = (f16)v.w;
        return a;
    };

    auto mfma_step = [&](f16x8 a0, f16x8 a1, const f16* wt, int Kh, int koff) {
        #pragma unroll
        for (int t = 0; t < 8; ++t) {
            f16x8 bf = *(const f16x8*)&wt[(size_t)(t * 16 + c) * Kh + koff + g * 8];
            acc[t][0] = __builtin_amdgcn_mfma_f32_16x16x32_f16(a0, bf, acc[t][0], 0, 0, 0);
            acc[t][1] = __builtin_amdgcn_mfma_f32_16x16x32_f16(a1, bf, acc[t][1], 0, 0, 0);
        }
    };

    // LayerNorm(+bias,gamma,beta)+ReLU on acc -> act (f16, wave-private rows), reset acc
    auto ln_relu_store = [&](const float* __restrict__ bias,
                             const float* __restrict__ gamma,
                             const float* __restrict__ beta) {
        float mu[2][4], rs[2][4];
        #pragma unroll
        for (int t = 0; t < 8; ++t) {
            float bt = bias[t * 16 + c];
            #pragma unroll
            for (int s = 0; s < 2; ++s)
                #pragma unroll
                for (int r = 0; r < 4; ++r) acc[t][s][r] += bt;
        }
        #pragma unroll
        for (int s = 0; s < 2; ++s)
            #pragma unroll
            for (int r = 0; r < 4; ++r) {
                float v = 0.f, q = 0.f;
                #pragma unroll
                for (int t = 0; t < 8; ++t) { float a = acc[t][s][r]; v += a; q += a * a; }
                #pragma unroll
                for (int m = 1; m < 16; m <<= 1) {
                    v += __shfl_xor(v, m, 64);
                    q += __shfl_xor(q, m, 64);
                }
                float mean = v * (1.0f / H);
                float var  = q * (1.0f / H) - mean * mean;
                mu[s][r] = mean;
                rs[s][r] = rsqrtf(var + 1e-5f);
            }
        #pragma unroll
        for (int t = 0; t < 8; ++t) {
            float gm = gamma[t * 16 + c];
            float bb = beta[t * 16 + c];
            #pragma unroll
            for (int s = 0; s < 2; ++s)
                #pragma unroll
                for (int r = 0; r < 4; ++r) {
                    float v = (acc[t][s][r] - mu[s][r]) * rs[s][r] * gm + bb;
                    v = fmaxf(v, 0.f);
                    act[(wrow + s * 16 + g * 4 + r) * PA + t * 16 + c] = (f16)v;
                }
        }
        #pragma unroll
        for (int t = 0; t < 8; ++t) {
            acc[t][0] = f32x4{0.f, 0.f, 0.f, 0.f};
            acc[t][1] = f32x4{0.f, 0.f, 0.f, 0.f};
        }
    };

    // ---------------- layer 1: concat(x[src],x[dst],edge) @ W0, K=384 ----------------
    const f16* w0t = wsW + W0T_OFF;
    #pragma unroll
    for (int kc = 0; kc < 4; ++kc) {
        int off = kc * 32 + g * 8;
        mfma_step(load_a(sp0, off), load_a(sp1, off), w0t, 384, kc * 32);
    }
    #pragma unroll
    for (int kc = 0; kc < 4; ++kc) {
        int off = kc * 32 + g * 8;
        mfma_step(load_a(dp0, off), load_a(dp1, off), w0t, 384, 128 + kc * 32);
    }
    #pragma unroll
    for (int kc = 0; kc < 4; ++kc) {
        int off = kc * 32 + g * 8;
        mfma_step(load_a(ep0, off), load_a(ep1, off), w0t, 384, 256 + kc * 32);
    }
    ln_relu_store(b0, g0, be0);

    // ---------------- layer 2: act @ W1, K=128 ----------------
    const f16* w1t = wsW + W1T_OFF;
    #pragma unroll
    for (int kc = 0; kc < 4; ++kc) {
        f16x8 a0 = *(const f16x8*)&act[(wrow + c) * PA + kc * 32 + g * 8];
        f16x8 a1 = *(const f16x8*)&act[(wrow + 16 + c) * PA + kc * 32 + g * 8];
        mfma_step(a0, a1, w1t, 128, kc * 32);
    }
    ln_relu_store(b1, g1, be1);

    // ---------------- layer 3: act @ W2, K=128 ----------------
    const f16* w2t = wsW + W2T_OFF;
    #pragma unroll
    for (int kc = 0; kc < 4; ++kc) {
        f16x8 a0 = *(const f16x8*)&act[(wrow + c) * PA + kc * 32 + g * 8];
        f16x8 a1 = *(const f16x8*)&act[(wrow + 16 + c) * PA + kc * 32 + g * 8];
        mfma_step(a0, a1, w2t, 128, kc * 32);
    }

    // ---------------- layer-3 LN+ReLU fused with dot(W3)+b3, direct store ----------------
    {
        float mu[2][4], rs[2][4];
        #pragma unroll
        for (int t = 0; t < 8; ++t) {
            float bt = b2[t * 16 + c];
            #pragma unroll
            for (int s = 0; s < 2; ++s)
                #pragma unroll
                for (int r = 0; r < 4; ++r) acc[t][s][r] += bt;
        }
        #pragma unroll
        for (int s = 0; s < 2; ++s)
            #pragma unroll
            for (int r = 0; r < 4; ++r) {
                float v = 0.f, q = 0.f;
                #pragma unroll
                for (int t = 0; t < 8; ++t) { float a = acc[t][s][r]; v += a; q += a * a; }
                #pragma unroll
                for (int m = 1; m < 16; m <<= 1) {
                    v += __shfl_xor(v, m, 64);
                    q += __shfl_xor(q, m, 64);
                }
                float mean = v * (1.0f / H);
                float var  = q * (1.0f / H) - mean * mean;
                mu[s][r] = mean;
                rs[s][r] = rsqrtf(var + 1e-5f);
            }
        float po[2][4] = {{0.f,0.f,0.f,0.f},{0.f,0.f,0.f,0.f}};
        #pragma unroll
        for (int t = 0; t < 8; ++t) {
            float gm  = g2[t * 16 + c];
            float bb  = be2[t * 16 + c];
            float w3v = W3[t * 16 + c];
            #pragma unroll
            for (int s = 0; s < 2; ++s)
                #pragma unroll
                for (int r = 0; r < 4; ++r) {
                    float v = (acc[t][s][r] - mu[s][r]) * rs[s][r] * gm + bb;
                    v = fmaxf(v, 0.f);
                    po[s][r] += v * w3v;
                }
        }
        float b3v = b3[0];
        #pragma unroll
        for (int s = 0; s < 2; ++s)
            #pragma unroll
            for (int r = 0; r < 4; ++r) {
                #pragma unroll
                for (int m = 1; m < 16; m <<= 1) po[s][r] += __shfl_xor(po[s][r], m, 64);
            }
        if (c == 0) {
            #pragma unroll
            for (int s = 0; s < 2; ++s)
                #pragma unroll
                for (int r = 0; r < 4; ++r) {
                    long long e = e0 + wrow + s * 16 + g * 4 + r;
                    if (e < E) out[e] = po[s][r] + b3v;
                }
        }
    }
}

extern "C" void kernel_launch(void* const* d_in, const int* in_sizes, int n_in,
                              void* d_out, int out_size, void* d_ws, size_t ws_size,
                              hipStream_t stream)
{
    const float* x    = (const float*)d_in[0];
    const int*   eidx = (const int*)d_in[1];     // int64 in reference -> int32 on device
    const float* edge = (const float*)d_in[2];
    const float* W0   = (const float*)d_in[3];
    const float* b0   = (const float*)d_in[4];
    const float* g0   = (const float*)d_in[5];
    const float* be0  = (const float*)d_in[6];
    const float* W1   = (const float*)d_in[7];
    const float* b1   = (const float*)d_in[8];
    const float* g1   = (const float*)d_in[9];
    const float* be1  = (const float*)d_in[10];
    const float* W2   = (const float*)d_in[11];
    const float* b2   = (const float*)d_in[12];
    const float* g2   = (const float*)d_in[13];
    const float* be2  = (const float*)d_in[14];
    const float* W3   = (const float*)d_in[15];
    const float* b3   = (const float*)d_in[16];
    float*       out  = (float*)d_out;
    f16*         wsW  = (f16*)d_ws;              // 160 KB of f16 W^T

    const int E = in_sizes[1] / 2;               // edge_index is (2, E)
    const int grid = (E + MT - 1) / MT;

    hipLaunchKernelGGL(prep_weights, dim3(80), dim3(256), 0, stream, W0, W1, W2, wsW);
    hipLaunchKernelGGL(edge_mlp, dim3(grid), dim3(256), 0, stream,
                       x, eidx, edge, wsW,
                       b0, g0, be0,
                       b1, g1, be1,
                       b2, g2, be2,
                       W3, b3, out, E);
}

// Round 4
// 792.069 us; speedup vs baseline: 1.0734x; 1.0734x over previous
//
#include <hip/hip_runtime.h>

typedef _Float16 f16;
typedef _Float16 f16x4 __attribute__((ext_vector_type(4)));
typedef _Float16 f16x8 __attribute__((ext_vector_type(8)));
typedef float    f32x4 __attribute__((ext_vector_type(4)));

static constexpr int H  = 128;
static constexpr int MT = 128;          // edges per block
static constexpr int PA = 136;          // act row stride in halves (16B-aligned: 272 B)
static constexpr int W0T_OFF = 0;                       // halves into ws
static constexpr int W1T_OFF = 128 * 384;
static constexpr int W2T_OFF = 128 * 384 + 128 * 128;   // total 81920 halves = 160 KB

// ---- prep: W (K x 128 f32, row-major) -> W^T (128 x K f16, k-contig) in ws ----
__global__ __launch_bounds__(256)
void prep_weights(const float* __restrict__ W0,
                  const float* __restrict__ W1,
                  const float* __restrict__ W2,
                  f16* __restrict__ o)
{
    int tid = blockIdx.x * 256 + threadIdx.x;
    const float* W; f16* dst; int K, idx;
    if (tid < 12288)      { W = W0; dst = o + W0T_OFF; K = 384; idx = tid; }
    else if (tid < 16384) { W = W1; dst = o + W1T_OFF; K = 128; idx = tid - 12288; }
    else if (tid < 20480) { W = W2; dst = o + W2T_OFF; K = 128; idx = tid - 16384; }
    else return;
    int n  = idx & 127;       // coalesced along n
    int k4 = idx >> 7;
    f16x4 v;
    #pragma unroll
    for (int j = 0; j < 4; ++j) v[j] = (f16)W[(k4 * 4 + j) * H + n];
    *(f16x4*)&dst[n * K + k4 * 4] = v;
}

// ---- fused edge MLP: zero barriers, wave-private M=32 tiles ----
// __launch_bounds__(256,3): 160-reg unified cap == actual allocation (96 VGPR +
// 64 AGPR acc). (256,4) capped at 128 and spilled acc -> 500 MB of scratch
// traffic (round-3 post-mortem). 3 blocks/CU; LDS 34.8 KB also allows >=3.
__global__ __launch_bounds__(256, 3)
void edge_mlp(const float* __restrict__ x,
              const int* __restrict__ eidx,
              const float* __restrict__ edge,
              const f16* __restrict__ wsW,
              const float* __restrict__ b0, const float* __restrict__ g0, const float* __restrict__ be0,
              const float* __restrict__ b1, const float* __restrict__ g1, const float* __restrict__ be1,
              const float* __restrict__ b2, const float* __restrict__ g2, const float* __restrict__ be2,
              const float* __restrict__ W3, const float* __restrict__ b3,
              float* __restrict__ out, int E)
{
    __shared__ f16 act[MT * PA];   // 34816 B

    const int tid  = threadIdx.x;
    const int lane = tid & 63;
    const int wid  = tid >> 6;
    const int c    = lane & 15;    // MFMA 16-dim coord
    const int g    = lane >> 4;    // quad group 0..3
    const int wrow = wid * 32;
    const long long e0 = (long long)blockIdx.x * MT;

    // this lane's two A-fragment rows (edges wrow+c and wrow+16+c)
    long long ea = e0 + wrow + c;      if (ea >= E) ea = (long long)E - 1;
    long long eb = e0 + wrow + 16 + c; if (eb >= E) eb = (long long)E - 1;
    const float* sp0 = x + (size_t)eidx[ea] * H;
    const float* sp1 = x + (size_t)eidx[eb] * H;
    const float* dp0 = x + (size_t)eidx[E + ea] * H;
    const float* dp1 = x + (size_t)eidx[E + eb] * H;
    const float* ep0 = edge + (size_t)ea * H;
    const float* ep1 = edge + (size_t)eb * H;

    f32x4 acc[8][2];
    #pragma unroll
    for (int t = 0; t < 8; ++t) {
        acc[t][0] = f32x4{0.f, 0.f, 0.f, 0.f};
        acc[t][1] = f32x4{0.f, 0.f, 0.f, 0.f};
    }

    auto load_a = [&](const float* p, int off) -> f16x8 {
        float4 u = *(const float4*)(p + off);
        float4 v = *(const float4*)(p + off + 4);
        f16x8 a;
        a[0] = (f16)u.x; a[1] = (f16)u.y; a[2] = (f16)u.z; a[3] = (f16)u.w;
        a[4] = (f16)v.x; a[5] = (f16)v.y; a[6] = (f16)v.z; a[7] = (f16)v.w;
        return a;
    };

    auto mfma_step = [&](f16x8 a0, f16x8 a1, const f16* wt, int Kh, int koff) {
        #pragma unroll
        for (int t = 0; t < 8; ++t) {
            f16x8 bf = *(const f16x8*)&wt[(size_t)(t * 16 + c) * Kh + koff + g * 8];
            acc[t][0] = __builtin_amdgcn_mfma_f32_16x16x32_f16(a0, bf, acc[t][0], 0, 0, 0);
            acc[t][1] = __builtin_amdgcn_mfma_f32_16x16x32_f16(a1, bf, acc[t][1], 0, 0, 0);
        }
    };

    // LayerNorm(+bias,gamma,beta)+ReLU on acc -> act (f16, wave-private rows), reset acc
    auto ln_relu_store = [&](const float* __restrict__ bias,
                             const float* __restrict__ gamma,
                             const float* __restrict__ beta) {
        float mu[2][4], rs[2][4];
        #pragma unroll
        for (int t = 0; t < 8; ++t) {
            float bt = bias[t * 16 + c];
            #pragma unroll
            for (int s = 0; s < 2; ++s)
                #pragma unroll
                for (int r = 0; r < 4; ++r) acc[t][s][r] += bt;
        }
        #pragma unroll
        for (int s = 0; s < 2; ++s)
            #pragma unroll
            for (int r = 0; r < 4; ++r) {
                float v = 0.f, q = 0.f;
                #pragma unroll
                for (int t = 0; t < 8; ++t) { float a = acc[t][s][r]; v += a; q += a * a; }
                #pragma unroll
                for (int m = 1; m < 16; m <<= 1) {
                    v += __shfl_xor(v, m, 64);
                    q += __shfl_xor(q, m, 64);
                }
                float mean = v * (1.0f / H);
                float var  = q * (1.0f / H) - mean * mean;
                mu[s][r] = mean;
                rs[s][r] = rsqrtf(var + 1e-5f);
            }
        #pragma unroll
        for (int t = 0; t < 8; ++t) {
            float gm = gamma[t * 16 + c];
            float bb = beta[t * 16 + c];
            #pragma unroll
            for (int s = 0; s < 2; ++s)
                #pragma unroll
                for (int r = 0; r < 4; ++r) {
                    float v = (acc[t][s][r] - mu[s][r]) * rs[s][r] * gm + bb;
                    v = fmaxf(v, 0.f);
                    act[(wrow + s * 16 + g * 4 + r) * PA + t * 16 + c] = (f16)v;
                }
        }
        #pragma unroll
        for (int t = 0; t < 8; ++t) {
            acc[t][0] = f32x4{0.f, 0.f, 0.f, 0.f};
            acc[t][1] = f32x4{0.f, 0.f, 0.f, 0.f};
        }
    };

    // ---------------- layer 1: concat(x[src],x[dst],edge) @ W0, K=384 ----------------
    const f16* w0t = wsW + W0T_OFF;
    #pragma unroll
    for (int kc = 0; kc < 4; ++kc) {
        int off = kc * 32 + g * 8;
        mfma_step(load_a(sp0, off), load_a(sp1, off), w0t, 384, kc * 32);
    }
    #pragma unroll
    for (int kc = 0; kc < 4; ++kc) {
        int off = kc * 32 + g * 8;
        mfma_step(load_a(dp0, off), load_a(dp1, off), w0t, 384, 128 + kc * 32);
    }
    #pragma unroll
    for (int kc = 0; kc < 4; ++kc) {
        int off = kc * 32 + g * 8;
        mfma_step(load_a(ep0, off), load_a(ep1, off), w0t, 384, 256 + kc * 32);
    }
    ln_relu_store(b0, g0, be0);

    // ---------------- layer 2: act @ W1, K=128 ----------------
    const f16* w1t = wsW + W1T_OFF;
    #pragma unroll
    for (int kc = 0; kc < 4; ++kc) {
        f16x8 a0 = *(const f16x8*)&act[(wrow + c) * PA + kc * 32 + g * 8];
        f16x8 a1 = *(const f16x8*)&act[(wrow + 16 + c) * PA + kc * 32 + g * 8];
        mfma_step(a0, a1, w1t, 128, kc * 32);
    }
    ln_relu_store(b1, g1, be1);

    // ---------------- layer 3: act @ W2, K=128 ----------------
    const f16* w2t = wsW + W2T_OFF;
    #pragma unroll
    for (int kc = 0; kc < 4; ++kc) {
        f16x8 a0 = *(const f16x8*)&act[(wrow + c) * PA + kc * 32 + g * 8];
        f16x8 a1 = *(const f16x8*)&act[(wrow + 16 + c) * PA + kc * 32 + g * 8];
        mfma_step(a0, a1, w2t, 128, kc * 32);
    }

    // ---------------- layer-3 LN+ReLU fused with dot(W3)+b3, direct store ----------------
    {
        float mu[2][4], rs[2][4];
        #pragma unroll
        for (int t = 0; t < 8; ++t) {
            float bt = b2[t * 16 + c];
            #pragma unroll
            for (int s = 0; s < 2; ++s)
                #pragma unroll
                for (int r = 0; r < 4; ++r) acc[t][s][r] += bt;
        }
        #pragma unroll
        for (int s = 0; s < 2; ++s)
            #pragma unroll
            for (int r = 0; r < 4; ++r) {
                float v = 0.f, q = 0.f;
                #pragma unroll
                for (int t = 0; t < 8; ++t) { float a = acc[t][s][r]; v += a; q += a * a; }
                #pragma unroll
                for (int m = 1; m < 16; m <<= 1) {
                    v += __shfl_xor(v, m, 64);
                    q += __shfl_xor(q, m, 64);
                }
                float mean = v * (1.0f / H);
                float var  = q * (1.0f / H) - mean * mean;
                mu[s][r] = mean;
                rs[s][r] = rsqrtf(var + 1e-5f);
            }
        float po[2][4] = {{0.f,0.f,0.f,0.f},{0.f,0.f,0.f,0.f}};
        #pragma unroll
        for (int t = 0; t < 8; ++t) {
            float gm  = g2[t * 16 + c];
            float bb  = be2[t * 16 + c];
            float w3v = W3[t * 16 + c];
            #pragma unroll
            for (int s = 0; s < 2; ++s)
                #pragma unroll
                for (int r = 0; r < 4; ++r) {
                    float v = (acc[t][s][r] - mu[s][r]) * rs[s][r] * gm + bb;
                    v = fmaxf(v, 0.f);
                    po[s][r] += v * w3v;
                }
        }
        float b3v = b3[0];
        #pragma unroll
        for (int s = 0; s < 2; ++s)
            #pragma unroll
            for (int r = 0; r < 4; ++r) {
                #pragma unroll
                for (int m = 1; m < 16; m <<= 1) po[s][r] += __shfl_xor(po[s][r], m, 64);
            }
        if (c == 0) {
            #pragma unroll
            for (int s = 0; s < 2; ++s)
                #pragma unroll
                for (int r = 0; r < 4; ++r) {
                    long long e = e0 + wrow + s * 16 + g * 4 + r;
                    if (e < E) out[e] = po[s][r] + b3v;
                }
        }
    }
}

extern "C" void kernel_launch(void* const* d_in, const int* in_sizes, int n_in,
                              void* d_out, int out_size, void* d_ws, size_t ws_size,
                              hipStream_t stream)
{
    const float* x    = (const float*)d_in[0];
    const int*   eidx = (const int*)d_in[1];     // int64 in reference -> int32 on device
    const float* edge = (const float*)d_in[2];
    const float* W0   = (const float*)d_in[3];
    const float* b0   = (const float*)d_in[4];
    const float* g0   = (const float*)d_in[5];
    const float* be0  = (const float*)d_in[6];
    const float* W1   = (const float*)d_in[7];
    const float* b1   = (const float*)d_in[8];
    const float* g1   = (const float*)d_in[9];
    const float* be1  = (const float*)d_in[10];
    const float* W2   = (const float*)d_in[11];
    const float* b2   = (const float*)d_in[12];
    const float* g2   = (const float*)d_in[13];
    const float* be2  = (const float*)d_in[14];
    const float* W3   = (const float*)d_in[15];
    const float* b3   = (const float*)d_in[16];
    float*       out  = (float*)d_out;
    f16*         wsW  = (f16*)d_ws;              // 160 KB of f16 W^T

    const int E = in_sizes[1] / 2;               // edge_index is (2, E)
    const int grid = (E + MT - 1) / MT;

    hipLaunchKernelGGL(prep_weights, dim3(80), dim3(256), 0, stream, W0, W1, W2, wsW);
    hipLaunchKernelGGL(edge_mlp, dim3(grid), dim3(256), 0, stream,
                       x, eidx, edge, wsW,
                       b0, g0, be0,
                       b1, g1, be1,
                       b2, g2, be2,
                       W3, b3, out, E);
}